// Round 4
// baseline (313.896 us; speedup 1.0000x reference)
//
#include <hip/hip_runtime.h>
#include <math.h>

#define NT 10          // thresholds
#define NC 22          // counters: tp[10], cnt[10], n_mask, n_tgt
#define BLOCK 256
#define MAXB 2048
#define WS_PART_OFF 64 // bytes reserved at start of ws for the layout flag

struct Logits { float L[NT]; };

// Probe: decide whether mask/target are 1-byte bools or int32 0/1.
// Bytes at offset 1 mod 4 are always 0 in int32-0/1 layout; ~50% nonzero
// per byte in bool8 layout. 64 samples from each array -> P(wrong) ~ 2^-128.
__global__ void pr_probe(const unsigned char* __restrict__ m,
                         const unsigned char* __restrict__ t,
                         unsigned* __restrict__ flag_out)
{
    const int idx = threadIdx.x;            // one wave: 0..63
    unsigned char a = m[idx * 4 + 1];
    unsigned char b = t[idx * 4 + 1];
    unsigned long long bal = __ballot(a | b);
    if (idx == 0) flag_out[0] = bal ? 1u : 0u;  // 1 = bool8, 0 = int32
}

// Kernel 1: grid-stride streaming count, dual-layout (uniform branch on flag).
// Per-thread register counters -> wave shuffle reduce -> LDS cross-wave ->
// per-block partials in d_ws (transposed [counter][block]). No atomics.
__global__ __launch_bounds__(BLOCK) void pr_count(
    const float* __restrict__ pred,
    const void* __restrict__ maskv,
    const void* __restrict__ targv,
    const unsigned* __restrict__ flag_p,
    unsigned* __restrict__ partials,
    int n, Logits lg)
{
    unsigned tp[NT], cnt[NT];
#pragma unroll
    for (int k = 0; k < NT; ++k) { tp[k] = 0u; cnt[k] = 0u; }
    unsigned nm = 0u, ntg = 0u;

    const unsigned flag = flag_p[0];  // wave-uniform
    const int stride = gridDim.x * blockDim.x;
    const int tid0 = blockIdx.x * blockDim.x + threadIdx.x;
    const int n4 = n >> 2;

    const float4* p4 = (const float4*)pred;

    if (flag) {
        // bool8 layout: pred float4 (16B/lane), mask/targ as packed 4 bytes (u32)
        const unsigned* m4 = (const unsigned*)maskv;
        const unsigned* t4 = (const unsigned*)targv;
#pragma unroll 2
        for (int i = tid0; i < n4; i += stride) {
            float4 p = p4[i];
            unsigned mw = m4[i];
            unsigned tw = t4[i];
            float pv[4] = { p.x, p.y, p.z, p.w };
#pragma unroll
            for (int j = 0; j < 4; ++j) {
                unsigned mb = (mw >> (8 * j)) & 0xffu;
                unsigned tb = (tw >> (8 * j)) & 0xffu;
                unsigned mm = mb ? 1u : 0u;
                unsigned tt = (tb && mb) ? 1u : 0u;
                nm += mm; ntg += tt;
#pragma unroll
                for (int k = 0; k < NT; ++k) {
                    bool pos = pv[j] > lg.L[k];
                    cnt[k] += pos ? mm : 0u;
                    tp[k]  += pos ? tt : 0u;
                }
            }
        }
    } else {
        // int32 layout: all three streams 16B/lane
        const int4* m4 = (const int4*)maskv;
        const int4* t4 = (const int4*)targv;
#pragma unroll 2
        for (int i = tid0; i < n4; i += stride) {
            float4 p = p4[i];
            int4 m = m4[i];
            int4 t = t4[i];
            float pv[4] = { p.x, p.y, p.z, p.w };
            int   mv[4] = { m.x, m.y, m.z, m.w };
            int   tv[4] = { t.x, t.y, t.z, t.w };
#pragma unroll
            for (int j = 0; j < 4; ++j) {
                unsigned mm = mv[j] ? 1u : 0u;
                unsigned tt = (tv[j] && mv[j]) ? 1u : 0u;
                nm += mm; ntg += tt;
#pragma unroll
                for (int k = 0; k < NT; ++k) {
                    bool pos = pv[j] > lg.L[k];
                    cnt[k] += pos ? mm : 0u;
                    tp[k]  += pos ? tt : 0u;
                }
            }
        }
    }

    // scalar tail (n % 4), one thread (dead when n % 4 == 0)
    if (tid0 == 0) {
        for (int i = n4 * 4; i < n; ++i) {
            unsigned mm, tt;
            if (flag) {
                unsigned mb = ((const unsigned char*)maskv)[i];
                unsigned tb = ((const unsigned char*)targv)[i];
                mm = mb ? 1u : 0u; tt = (tb && mb) ? 1u : 0u;
            } else {
                int mvv = ((const int*)maskv)[i];
                int tvv = ((const int*)targv)[i];
                mm = mvv ? 1u : 0u; tt = (tvv && mvv) ? 1u : 0u;
            }
            nm += mm; ntg += tt;
            for (int k = 0; k < NT; ++k) {
                bool pos = pred[i] > lg.L[k];
                cnt[k] += pos ? mm : 0u;
                tp[k]  += pos ? tt : 0u;
            }
        }
    }

    // wave (64-lane) butterfly reduction
#pragma unroll
    for (int off = 32; off; off >>= 1) {
        nm  += __shfl_down(nm, off);
        ntg += __shfl_down(ntg, off);
#pragma unroll
        for (int k = 0; k < NT; ++k) {
            tp[k]  += __shfl_down(tp[k], off);
            cnt[k] += __shfl_down(cnt[k], off);
        }
    }

    __shared__ unsigned red[BLOCK / 64][NC];
    const int lane = threadIdx.x & 63;
    const int wid = threadIdx.x >> 6;
    if (lane == 0) {
#pragma unroll
        for (int k = 0; k < NT; ++k) {
            red[wid][k] = tp[k];
            red[wid][NT + k] = cnt[k];
        }
        red[wid][20] = nm;
        red[wid][21] = ntg;
    }
    __syncthreads();
    if (threadIdx.x < NC) {
        unsigned s = 0u;
#pragma unroll
        for (int w = 0; w < BLOCK / 64; ++w) s += red[w][threadIdx.x];
        partials[threadIdx.x * gridDim.x + blockIdx.x] = s;
    }
}

// Kernel 2: fold per-block partials, compute fp/tn/fn, write 40 int32.
__global__ __launch_bounds__(BLOCK) void pr_final(
    const unsigned* __restrict__ partials, int nb, int* __restrict__ out)
{
    __shared__ unsigned wred[NC][BLOCK / 64];
    __shared__ unsigned tot[NC];
    const int tid = threadIdx.x;
    const int lane = tid & 63;
    const int wid = tid >> 6;

    for (int c = 0; c < NC; ++c) {
        unsigned s = 0u;
        for (int i = tid; i < nb; i += BLOCK) s += partials[c * nb + i];
#pragma unroll
        for (int off = 32; off; off >>= 1) s += __shfl_down(s, off);
        if (lane == 0) wred[c][wid] = s;
    }
    __syncthreads();
    if (tid < NC) {
        unsigned s = 0u;
#pragma unroll
        for (int w = 0; w < BLOCK / 64; ++w) s += wred[tid][w];
        tot[tid] = s;
    }
    __syncthreads();
    if (tid < 4 * NT) {
        const int row = tid / NT, k = tid % NT;
        const unsigned tpv = tot[k], cntv = tot[NT + k];
        const unsigned nmv = tot[20], ntgv = tot[21];
        const unsigned fpv = cntv - tpv;
        const unsigned fnv = ntgv - tpv;
        const unsigned tnv = nmv - cntv - fnv;
        unsigned v = (row == 0) ? tpv : (row == 1) ? fpv : (row == 2) ? tnv : fnv;
        out[tid] = (int)v;   // raw int32 — harness reads int32
    }
}

extern "C" void kernel_launch(void* const* d_in, const int* in_sizes, int n_in,
                              void* d_out, int out_size, void* d_ws, size_t ws_size,
                              hipStream_t stream) {
    const float* pred = (const float*)d_in[0];
    const void* mask = d_in[1];
    const void* targ = d_in[2];
    const int n = in_sizes[0];

    unsigned* flag = (unsigned*)d_ws;
    unsigned* partials = (unsigned*)((char*)d_ws + WS_PART_OFF);

    int nb = MAXB;
    const size_t need_per_block = (size_t)NC * sizeof(unsigned);
    if (ws_size < WS_PART_OFF + (size_t)nb * need_per_block)
        nb = (int)((ws_size - WS_PART_OFF) / need_per_block);
    if (nb < 1) nb = 1;

    // thresholds: linspace(0,1,12)[1:-1] in f32 -> logit in f64 ->
    // largest f32 <= logit so (p_f32 > L) == (sigmoid_exact(p) > th_f32)
    Logits lg;
    const float step = 1.0f / 11.0f;
    for (int k = 0; k < NT; ++k) {
        float th = (float)(k + 1) * step;
        double lo = log((double)th / (1.0 - (double)th));
        float L = (float)lo;
        if ((double)L > lo) L = nextafterf(L, -INFINITY);
        lg.L[k] = L;
    }

    pr_probe<<<1, 64, 0, stream>>>((const unsigned char*)mask,
                                   (const unsigned char*)targ, flag);
    pr_count<<<nb, BLOCK, 0, stream>>>(pred, mask, targ, flag, partials, n, lg);
    pr_final<<<1, BLOCK, 0, stream>>>(partials, nb, (int*)d_out);
}

// Round 12
// 312.173 us; speedup vs baseline: 1.0055x; 1.0055x over previous
//
#include <hip/hip_runtime.h>
#include <math.h>

#define NT 10          // thresholds
#define NC 22          // counters: tp[10], cnt[10], n_mask, n_tgt
#define BLOCK 256
#define NBLK 2048
#define WS_PART_OFF 64 // bytes reserved at start of ws for the layout flag

struct Logits { float L[NT]; };

// Round-9 lesson: mask/target are int32 0/1 (bool8 misread explains the exact
// deterministic absmax 4.67e6 = counts collapsed to ~1/4). Round-4 passed via
// its probe-selected INT32 path, not bool8; FETCH 147.5MB was L3 absorption.
// Keep probe + dual path so layout can never silently break correctness again.

static __device__ __forceinline__ unsigned norm01(unsigned x) {
    unsigned t = x | (x >> 1);
    t |= t >> 2;
    t |= t >> 4;
    return t & 0x01010101u;
}

// Probe: bytes at offset 1 mod 4 are always 0 in int32-0/1 layout; ~50%
// nonzero in bool8 layout. P(misclassify) ~ 2^-128 on random bools.
__global__ void pr_probe(const unsigned char* __restrict__ m,
                         const unsigned char* __restrict__ t,
                         unsigned* __restrict__ flag_out)
{
    const int idx = threadIdx.x;            // one wave: 0..63
    unsigned char a = m[idx * 4 + 1];
    unsigned char b = t[idx * 4 + 1];
    unsigned long long bal = __ballot(a | b);
    if (idx == 0) flag_out[0] = bal ? 1u : 0u;  // 1 = bool8, 0 = int32
}

// Kernel 1: grid-stride count. int32 path: 8 elem/iter via 6 independent wide
// loads (2x float4 + 2x uint4 mask + 2x uint4 targ = 96 B/lane in flight).
// Packed (cnt,tp) u32 counters: low16 = pos&mask, high16 = pos&mask&target.
// Per-thread elements <= 48 (nb=2048) so fields never overflow; wave <= 3072.
__global__ __launch_bounds__(BLOCK) void pr_count(
    const float4* __restrict__ pred4,
    const void* __restrict__ maskv,
    const void* __restrict__ targv,
    const unsigned* __restrict__ flag_p,
    unsigned* __restrict__ partials,
    int n, Logits lg)
{
    unsigned combo[NT];           // low16 = cnt, high16 = tp
#pragma unroll
    for (int k = 0; k < NT; ++k) combo[k] = 0u;
    unsigned nmtg = 0u;           // low16 = n_mask, high16 = n_tgt

    const unsigned flag = flag_p[0];  // wave-uniform
    const int stride = gridDim.x * blockDim.x;
    const int tid0 = blockIdx.x * blockDim.x + threadIdx.x;

    if (!flag) {
        // int32 0/1 layout (the real one): 8 elements/iteration
        const uint4* m4 = (const uint4*)maskv;
        const uint4* t4 = (const uint4*)targv;
        const int n8 = n >> 3;
        for (int g = tid0; g < n8; g += stride) {
            // 6 independent loads, issued before any use
            float4 p0 = pred4[2 * g + 0];
            float4 p1 = pred4[2 * g + 1];
            uint4 mw0 = m4[2 * g + 0];
            uint4 mw1 = m4[2 * g + 1];
            uint4 tw0 = t4[2 * g + 0];
            uint4 tw1 = t4[2 * g + 1];
            float    pj[8] = { p0.x, p0.y, p0.z, p0.w, p1.x, p1.y, p1.z, p1.w };
            unsigned mv[8] = { mw0.x, mw0.y, mw0.z, mw0.w, mw1.x, mw1.y, mw1.z, mw1.w };
            unsigned tv[8] = { tw0.x, tw0.y, tw0.z, tw0.w, tw1.x, tw1.y, tw1.z, tw1.w };
#pragma unroll
            for (int j = 0; j < 8; ++j) {
                unsigned mm = mv[j] ? 1u : 0u;            // normalize (proven r4)
                unsigned tt = (mv[j] && tv[j]) ? 1u : 0u;
                unsigned pair = mm | (tt << 16);
                nmtg += pair;
#pragma unroll
                for (int k = 0; k < NT; ++k)
                    combo[k] += (pj[j] > lg.L[k]) ? pair : 0u;
            }
        }
        // scalar tail (n % 8), one thread (dead for this shape)
        if (tid0 == 0) {
            const float* pred = (const float*)pred4;
            const int* m = (const int*)maskv;
            const int* t = (const int*)targv;
            for (int i = n8 * 8; i < n; ++i) {
                unsigned mm = m[i] ? 1u : 0u;
                unsigned tt = (m[i] && t[i]) ? 1u : 0u;
                unsigned pair = mm | (tt << 16);
                nmtg += pair;
                for (int k = 0; k < NT; ++k)
                    combo[k] += (pred[i] > lg.L[k]) ? pair : 0u;
            }
        }
    } else {
        // bool8 fallback: 16 elements/iteration, byte-normalized
        const uint4* m16 = (const uint4*)maskv;
        const uint4* t16 = (const uint4*)targv;
        const int n16 = n >> 4;
        for (int g = tid0; g < n16; g += stride) {
            float4 p0 = pred4[4 * g + 0];
            float4 p1 = pred4[4 * g + 1];
            float4 p2 = pred4[4 * g + 2];
            float4 p3 = pred4[4 * g + 3];
            uint4 mwv = m16[g];
            uint4 twv = t16[g];
            float4 P[4] = { p0, p1, p2, p3 };
            unsigned MW[4] = { norm01(mwv.x), norm01(mwv.y), norm01(mwv.z), norm01(mwv.w) };
            unsigned TW[4] = { norm01(twv.x), norm01(twv.y), norm01(twv.z), norm01(twv.w) };
#pragma unroll
            for (int q = 0; q < 4; ++q) {
                float pj[4] = { P[q].x, P[q].y, P[q].z, P[q].w };
                const unsigned mword = MW[q], tword = TW[q];
#pragma unroll
                for (int j = 0; j < 4; ++j) {
                    unsigned mb = (mword >> (8 * j)) & 1u;
                    unsigned tb = (tword >> (8 * j)) & 1u;
                    unsigned pair = mb | ((mb & tb) << 16);
                    nmtg += pair;
#pragma unroll
                    for (int k = 0; k < NT; ++k)
                        combo[k] += (pj[j] > lg.L[k]) ? pair : 0u;
                }
            }
        }
        if (tid0 == 0) {
            const float* pred = (const float*)pred4;
            const unsigned char* m = (const unsigned char*)maskv;
            const unsigned char* t = (const unsigned char*)targv;
            for (int i = n16 * 16; i < n; ++i) {
                unsigned mm = m[i] ? 1u : 0u;
                unsigned tt = (m[i] && t[i]) ? 1u : 0u;
                unsigned pair = mm | (tt << 16);
                nmtg += pair;
                for (int k = 0; k < NT; ++k)
                    combo[k] += (pred[i] > lg.L[k]) ? pair : 0u;
            }
        }
    }

    // wave (64-lane) butterfly reduction: 11 packed values
#pragma unroll
    for (int off = 32; off; off >>= 1) {
        nmtg += __shfl_down(nmtg, off);
#pragma unroll
        for (int k = 0; k < NT; ++k)
            combo[k] += __shfl_down(combo[k], off);
    }

    __shared__ unsigned red[BLOCK / 64][NC];
    const int lane = threadIdx.x & 63;
    const int wid = threadIdx.x >> 6;
    if (lane == 0) {
#pragma unroll
        for (int k = 0; k < NT; ++k) {
            red[wid][k]      = combo[k] >> 16;       // tp
            red[wid][NT + k] = combo[k] & 0xffffu;   // cnt
        }
        red[wid][20] = nmtg & 0xffffu;               // n_mask
        red[wid][21] = nmtg >> 16;                   // n_tgt
    }
    __syncthreads();
    if (threadIdx.x < NC) {
        unsigned s = 0u;
#pragma unroll
        for (int w = 0; w < BLOCK / 64; ++w) s += red[w][threadIdx.x];
        // transposed: [counter][block] for coalesced kernel-2 reads
        partials[threadIdx.x * gridDim.x + blockIdx.x] = s;
    }
}

// Kernel 2: fold per-block partials, compute fp/tn/fn, write 40 int32.
__global__ __launch_bounds__(BLOCK) void pr_final(
    const unsigned* __restrict__ partials, int nb, int* __restrict__ out)
{
    __shared__ unsigned wred[NC][BLOCK / 64];
    __shared__ unsigned tot[NC];
    const int tid = threadIdx.x;
    const int lane = tid & 63;
    const int wid = tid >> 6;

    for (int c = 0; c < NC; ++c) {
        unsigned s = 0u;
        for (int i = tid; i < nb; i += BLOCK) s += partials[c * nb + i];
#pragma unroll
        for (int off = 32; off; off >>= 1) s += __shfl_down(s, off);
        if (lane == 0) wred[c][wid] = s;
    }
    __syncthreads();
    if (tid < NC) {
        unsigned s = 0u;
#pragma unroll
        for (int w = 0; w < BLOCK / 64; ++w) s += wred[tid][w];
        tot[tid] = s;
    }
    __syncthreads();
    if (tid < 4 * NT) {
        const int row = tid / NT, k = tid % NT;
        const unsigned tpv = tot[k], cntv = tot[NT + k];
        const unsigned nmv = tot[20], ntgv = tot[21];
        const unsigned fpv = cntv - tpv;
        const unsigned fnv = ntgv - tpv;
        const unsigned tnv = nmv - cntv - fnv;
        unsigned v = (row == 0) ? tpv : (row == 1) ? fpv : (row == 2) ? tnv : fnv;
        out[tid] = (int)v;   // raw int32 — harness reads int32
    }
}

extern "C" void kernel_launch(void* const* d_in, const int* in_sizes, int n_in,
                              void* d_out, int out_size, void* d_ws, size_t ws_size,
                              hipStream_t stream) {
    const float* pred = (const float*)d_in[0];
    const void* mask = d_in[1];
    const void* targ = d_in[2];
    const int n = in_sizes[0];

    unsigned* flag = (unsigned*)d_ws;
    unsigned* partials = (unsigned*)((char*)d_ws + WS_PART_OFF);

    int nb = NBLK;
    const size_t need_per_block = (size_t)NC * sizeof(unsigned);
    if (ws_size < WS_PART_OFF + (size_t)nb * need_per_block)
        nb = (int)((ws_size - WS_PART_OFF) / need_per_block);
    if (nb < 1) nb = 1;

    // thresholds: linspace(0,1,12)[1:-1] in f32 -> logit in f64 ->
    // largest f32 <= logit so (p_f32 > L) == (sigmoid_exact(p) > th_f32)
    Logits lg;
    const float step = 1.0f / 11.0f;
    for (int k = 0; k < NT; ++k) {
        float th = (float)(k + 1) * step;
        double lo = log((double)th / (1.0 - (double)th));
        float L = (float)lo;
        if ((double)L > lo) L = nextafterf(L, -INFINITY);
        lg.L[k] = L;
    }

    pr_probe<<<1, 64, 0, stream>>>((const unsigned char*)mask,
                                   (const unsigned char*)targ, flag);
    pr_count<<<nb, BLOCK, 0, stream>>>((const float4*)pred, mask, targ,
                                       flag, partials, n, lg);
    pr_final<<<1, BLOCK, 0, stream>>>(partials, nb, (int*)d_out);
}